// Round 13
// baseline (188.388 us; speedup 1.0000x reference)
//
#include <hip/hip_runtime.h>
#include <cstdint>

#define D_MODEL 1536
#define BATCH   8192
#define EPS     1e-8f

#define BM 128
#define BN 96        // multiple of 3: quaternion blocks never straddle a tile
#define BK 64
#define NTN (D_MODEL / BN)   // 16
#define NTM (BATCH / BM)     // 64

typedef __attribute__((ext_vector_type(8))) short bf16x8;
typedef __attribute__((ext_vector_type(8))) unsigned short ushort8;
typedef __attribute__((ext_vector_type(4))) float f32x4;

__device__ __forceinline__ unsigned short f2bf(float f) {
  unsigned u = __builtin_bit_cast(unsigned, f);
  u += 0x7fffu + ((u >> 16) & 1u);            // round-to-nearest-even
  return (unsigned short)(u >> 16);
}

__device__ __forceinline__ ushort8 pack8u(float4 a, float4 b) {
  ushort8 o;
  o[0] = f2bf(a.x); o[1] = f2bf(a.y); o[2] = f2bf(a.z); o[3] = f2bf(a.w);
  o[4] = f2bf(b.x); o[5] = f2bf(b.y); o[6] = f2bf(b.z); o[7] = f2bf(b.w);
  return o;
}

__device__ __forceinline__ void full_drain() {
  asm volatile("s_waitcnt vmcnt(0) lgkmcnt(0)" ::: "memory");
}

__device__ __forceinline__ void load_lds16(const void* g, void* l) {
  __builtin_amdgcn_global_load_lds(
      (const __attribute__((address_space(1))) unsigned int*)g,
      (__attribute__((address_space(3))) unsigned int*)l,
      16, 0, 0);
}

// ---------------- prep: f32 -> bf16 for x, W_biv, W_in -------------------
__global__ void prep_kernel(const float* __restrict__ x,
                            const float* __restrict__ wbiv,
                            const float* __restrict__ win,
                            unsigned short* __restrict__ xb,
                            unsigned short* __restrict__ wb) {
  const long NX4 = (long)BATCH * D_MODEL / 4;     // 3145728
  const long NW4 = (long)D_MODEL * D_MODEL / 4;   // 589824
  const long total = NX4 + 2 * NW4;
  for (long i = (long)blockIdx.x * blockDim.x + threadIdx.x; i < total;
       i += (long)gridDim.x * blockDim.x) {
    const float4* src; unsigned short* dst; long j;
    if (i < NX4)            { src = (const float4*)x;    dst = xb; j = i; }
    else if (i < NX4 + NW4) { src = (const float4*)wbiv; dst = wb; j = i - NX4; }
    else                    { src = (const float4*)win;
                              dst = wb + (long)D_MODEL * D_MODEL; j = i - NX4 - NW4; }
    float4 v = src[j];
    ushort4 o;
    o.x = f2bf(v.x); o.y = f2bf(v.y); o.z = f2bf(v.z); o.w = f2bf(v.w);
    *(ushort4*)(dst + 4 * j) = o;
  }
}

// ---------------- decay: sigmoid(x . w_dec + b_dec), wave per row ---------
__global__ void decay_kernel(const float* __restrict__ x,
                             const float* __restrict__ wdec,
                             const float* __restrict__ bdec,
                             float* __restrict__ decay) {
  int row  = (int)((blockIdx.x * blockDim.x + threadIdx.x) >> 6);
  int lane = threadIdx.x & 63;
  if (row >= BATCH) return;
  const float4* xr = (const float4*)(x + (long)row * D_MODEL);
  const float4* wr = (const float4*)wdec;
  float acc = 0.f;
#pragma unroll
  for (int i = 0; i < 6; ++i) {
    float4 a = xr[lane + 64 * i];
    float4 b = wr[lane + 64 * i];
    acc += a.x * b.x + a.y * b.y + a.z * b.z + a.w * b.w;
  }
  for (int off = 32; off; off >>= 1) acc += __shfl_xor(acc, off);
  if (lane == 0) decay[row] = 1.f / (1.f + expf(-(acc + bdec[0])));
}

// ---------------- main: dual-GEMM + quaternion epilogue -------------------
// 512 threads / 8 waves (4x2 grid, 32x48 per wave). Merged-ks: ONE fence
// region per K-tile. launch_bounds(512,2): 256-VGPR cap, NO spill pressure
// (r12's failure isolated to the (512,6) 85-reg cap forcing spills).
__global__ __launch_bounds__(512, 2)
void fused_main(const unsigned short* __restrict__ xb,
                const unsigned short* __restrict__ wb,
                const float* __restrict__ hprev,
                const float* __restrict__ decay,
                const float* __restrict__ bbiv,
                const float* __restrict__ bin,
                float* __restrict__ out) {
  __shared__ __align__(16) char smem[50688];
  __shared__ float sDecay[BM];
  unsigned short* sA  = (unsigned short*)smem;             // [128][64] bf16
  unsigned short* sB1 = (unsigned short*)(smem + 16384);   // [96][64]
  unsigned short* sB2 = (unsigned short*)(smem + 28672);   // [96][64]
  float* sBv = (float*)smem;                               // [128][97] overlay

  const int bid = blockIdx.x;
  const int tm = bid / NTN, tn = bid % NTN;
  const int m0 = tm * BM, n0 = tn * BN;
  const int tid  = threadIdx.x;
  const int lane = tid & 63, wid = tid >> 6;
  const int wr = wid >> 1, wc = wid & 1;   // 4x2 wave grid: 32x48 per wave
  const int lr = lane & 15;                // fragment row/col
  const int lk = lane >> 4;                // k-octet group

  if (tid < BM) sDecay[tid] = decay[m0 + tid];   // published by first barrier

  // acc*[mi][ni][r] == C[wr*32+mi*16+lk*4+r][n0+wc*48+ni*16+lr]
  f32x4 accB[2][3], accI[2][3];
#pragma unroll
  for (int a = 0; a < 2; ++a)
#pragma unroll
    for (int b = 0; b < 3; ++b) { accB[a][b] = (f32x4)0.f; accI[a][b] = (f32x4)0.f; }

  for (int kt = 0; kt < D_MODEL; kt += BK) {
    full_drain();
    __syncthreads();
    // ---- stage A (128x64 bf16): linear LDS dest, source slot swizzled ----
#pragma unroll
    for (int i = 0; i < 2; ++i) {
      int f = i * 512 + tid;               // [0,1024)
      int row = f >> 3, c = f & 7;
      int cs = c ^ (row & 7);              // inverse-swizzled source slot
      const unsigned short* g = xb + (long)(m0 + row) * D_MODEL + kt + cs * 8;
      load_lds16(g, smem + ((i * 512 + wid * 64) << 4));
    }
    // ---- stage B1 = W_biv rows (768 chunks) ----
    {
      int f = tid;
      int row = f >> 3, c = f & 7, cs = c ^ (row & 7);
      const unsigned short* g = wb + (long)(n0 + row) * D_MODEL + kt + cs * 8;
      load_lds16(g, smem + 16384 + ((wid * 64) << 4));
    }
    if (tid < 256) {
      int f = 512 + tid;
      int row = f >> 3, c = f & 7, cs = c ^ (row & 7);
      const unsigned short* g = wb + (long)(n0 + row) * D_MODEL + kt + cs * 8;
      load_lds16(g, smem + 16384 + ((512 + wid * 64) << 4));
    }
    // ---- stage B2 = W_in rows (768 chunks) ----
    {
      int f = tid;
      int row = f >> 3, c = f & 7, cs = c ^ (row & 7);
      const unsigned short* g = wb + (long)(D_MODEL + n0 + row) * D_MODEL + kt + cs * 8;
      load_lds16(g, smem + 28672 + ((wid * 64) << 4));
    }
    if (tid < 256) {
      int f = 512 + tid;
      int row = f >> 3, c = f & 7, cs = c ^ (row & 7);
      const unsigned short* g = wb + (long)(D_MODEL + n0 + row) * D_MODEL + kt + cs * 8;
      load_lds16(g, smem + 28672 + ((512 + wid * 64) << 4));
    }
    full_drain();                          // global_load_lds data landed
    __syncthreads();

    // ---- MFMA core: ONE fence region per K-tile (merged ks) ----
    {
      bf16x8 a[2][2], b1[3][2], b2[3][2];
#pragma unroll
      for (int ks = 0; ks < 2; ++ks) {
        const int slot = ks * 4 + lk;      // logical k-octet slot (0..7)
#pragma unroll
        for (int mi = 0; mi < 2; ++mi) {
          int R = wr * 32 + mi * 16 + lr;
          a[mi][ks] = *(const bf16x8*)(sA + R * 64 + (slot ^ (R & 7)) * 8);
        }
#pragma unroll
        for (int ni = 0; ni < 3; ++ni) {
          int R = wc * 48 + ni * 16 + lr;
          b1[ni][ks] = *(const bf16x8*)(sB1 + R * 64 + (slot ^ (R & 7)) * 8);
          b2[ni][ks] = *(const bf16x8*)(sB2 + R * 64 + (slot ^ (R & 7)) * 8);
        }
      }
      full_drain();                          // all LDS reads complete
      __builtin_amdgcn_sched_barrier(0);     // operands finalized before MFMAs
#pragma unroll
      for (int ks = 0; ks < 2; ++ks)
#pragma unroll
        for (int mi = 0; mi < 2; ++mi)
#pragma unroll
          for (int ni = 0; ni < 3; ++ni)
            accB[mi][ni] = __builtin_amdgcn_mfma_f32_16x16x32_bf16(
                a[mi][ks], b1[ni][ks], accB[mi][ni], 0, 0, 0);
      __builtin_amdgcn_sched_barrier(0);     // no chain interleave
#pragma unroll
      for (int ks = 0; ks < 2; ++ks)
#pragma unroll
        for (int mi = 0; mi < 2; ++mi)
#pragma unroll
          for (int ni = 0; ni < 3; ++ni)
            accI[mi][ni] = __builtin_amdgcn_mfma_f32_16x16x32_bf16(
                a[mi][ks], b2[ni][ks], accI[mi][ni], 0, 0, 0);
      __builtin_amdgcn_sched_barrier(0);
    }
  }

  // ---- epilogue (green r11 logic) ----
  full_drain();
  __syncthreads();
#pragma unroll
  for (int mi = 0; mi < 2; ++mi)
#pragma unroll
    for (int ni = 0; ni < 3; ++ni) {
      int col = wc * 48 + ni * 16 + lr;
      float bb = bbiv[n0 + col];
#pragma unroll
      for (int r = 0; r < 4; ++r) {
        int row = wr * 32 + mi * 16 + lk * 4 + r;
        sBv[row * 97 + col] = accB[mi][ni][r] + bb;
      }
    }
  full_drain();
  __syncthreads();

#pragma unroll
  for (int mi = 0; mi < 2; ++mi)
#pragma unroll
    for (int ni = 0; ni < 3; ++ni) {
      int col  = wc * 48 + ni * 16 + lr;
      int gcol = n0 + col;
      int c    = (col % 3);        // n0 % 3 == 0
      int lc0  = col - c;
      float binv = bin[gcol];
#pragma unroll
      for (int r = 0; r < 4; ++r) {
        int row  = wr * 32 + mi * 16 + lk * 4 + r;
        int grow = m0 + row;
        float bx = sBv[row * 97 + lc0];
        float by = sBv[row * 97 + lc0 + 1];
        float bz = sBv[row * 97 + lc0 + 2];
        const float* hp = hprev + (long)grow * D_MODEL + (n0 + lc0);
        float vx = hp[0], vy = hp[1], vz = hp[2];
        float nb = sqrtf(bx * bx + by * by + bz * bz);
        nb = fmaxf(nb, EPS);
        float ha = 0.5f * nb;
        float w  = cosf(ha);
        float s  = sinf(ha) / nb;
        // faithful to reference quirk: qx from bz, qy from -by, qz from bx
        float qx = s * bz, qy = -s * by, qz = s * bx;
        float tx = 2.f * (qy * vz - qz * vy);
        float ty = 2.f * (qz * vx - qx * vz);
        float tz = 2.f * (qx * vy - qy * vx);
        float rx = vx + w * tx + (qy * tz - qz * ty);
        float ry = vy + w * ty + (qz * tx - qx * tz);
        float rz = vz + w * tz + (qx * ty - qy * tx);
        float rc = (c == 0) ? rx : ((c == 1) ? ry : rz);
        out[(long)grow * D_MODEL + gcol] =
            sDecay[row] * rc + (accI[mi][ni][r] + binv);
      }
    }
}

// ---------------- fallback (r7 green kernel, hammers retained) ------------
__global__ __launch_bounds__(256, 2)
void fused_mfma3(const float* __restrict__ x,
                 const float* __restrict__ wbiv,
                 const float* __restrict__ win,
                 const float* __restrict__ hprev,
                 const float* __restrict__ wdec,
                 const float* __restrict__ bdec,
                 const float* __restrict__ bbiv,
                 const float* __restrict__ bin,
                 float* __restrict__ out) {
  __shared__ __align__(16) char smem[50688];
  __shared__ float sDecay[BM];
  unsigned short* sA  = (unsigned short*)smem;
  unsigned short* sB1 = (unsigned short*)(smem + 16384);
  unsigned short* sB2 = (unsigned short*)(smem + 28672);
  float* sBv = (float*)smem;

  const int bid = blockIdx.x;
  const int tm = bid / NTN, tn = bid % NTN;
  const int m0 = tm * BM, n0 = tn * BN;
  const int tid  = threadIdx.x;
  const int lane = tid & 63, wid = tid >> 6;
  const int wr = wid >> 1, wc = wid & 1;
  const int lr = lane & 15;
  const int lk = lane >> 4;

  {
    const float bd = bdec[0];
    const float4* wd4 = (const float4*)wdec;
    for (int rr = 0; rr < 32; ++rr) {
      int row = wid * 32 + rr;
      const float4* xr = (const float4*)(x + (long)(m0 + row) * D_MODEL);
      float acc = 0.f;
#pragma unroll
      for (int i = 0; i < 6; ++i) {
        float4 a = xr[lane + 64 * i];
        float4 b = wd4[lane + 64 * i];
        acc += a.x * b.x + a.y * b.y + a.z * b.z + a.w * b.w;
      }
      for (int off = 32; off; off >>= 1) acc += __shfl_xor(acc, off);
      if (lane == 0) sDecay[row] = 1.f / (1.f + expf(-(acc + bd)));
    }
  }

  f32x4 accB[4][3], accI[4][3];
#pragma unroll
  for (int a = 0; a < 4; ++a)
#pragma unroll
    for (int b = 0; b < 3; ++b) { accB[a][b] = (f32x4)0.f; accI[a][b] = (f32x4)0.f; }

  for (int kt = 0; kt < D_MODEL; kt += BK) {
    full_drain();
    __syncthreads();
#pragma unroll
    for (int i = 0; i < 4; ++i) {
      int f = i * 256 + tid;
      int row = f >> 3, c = f & 7;
      const float4* p = (const float4*)(x + (long)(m0 + row) * D_MODEL + kt + c * 8);
      *(ushort8*)(sA + row * 64 + c * 8) = pack8u(p[0], p[1]);
    }
#pragma unroll
    for (int i = 0; i < 6; ++i) {
      int mat = (i >= 3);
      int g = (i - 3 * mat) * 256 + tid;
      int row = g >> 3, c = g & 7;
      const float* wsrc = mat ? win : wbiv;
      const float4* p = (const float4*)(wsrc + (long)(n0 + row) * D_MODEL + kt + c * 8);
      *(ushort8*)((mat ? sB2 : sB1) + row * 64 + c * 8) = pack8u(p[0], p[1]);
    }
    full_drain();
    __syncthreads();

#pragma unroll
    for (int ks = 0; ks < 2; ++ks) {
      const int k0 = ks * 32 + lk * 8;
      bf16x8 a[4], b1[3], b2[3];
#pragma unroll
      for (int mi = 0; mi < 4; ++mi)
        a[mi] = *(const bf16x8*)(sA + (wr * 64 + mi * 16 + lr) * 64 + k0);
#pragma unroll
      for (int ni = 0; ni < 3; ++ni) {
        b1[ni] = *(const bf16x8*)(sB1 + (wc * 48 + ni * 16 + lr) * 64 + k0);
        b2[ni] = *(const bf16x8*)(sB2 + (wc * 48 + ni * 16 + lr) * 64 + k0);
      }
      full_drain();
      __builtin_amdgcn_sched_barrier(0);
#pragma unroll
      for (int mi = 0; mi < 4; ++mi)
#pragma unroll
        for (int ni = 0; ni < 3; ++ni)
          accB[mi][ni] = __builtin_amdgcn_mfma_f32_16x16x32_bf16(
              a[mi], b1[ni], accB[mi][ni], 0, 0, 0);
      __builtin_amdgcn_sched_barrier(0);
#pragma unroll
      for (int mi = 0; mi < 4; ++mi)
#pragma unroll
        for (int ni = 0; ni < 3; ++ni)
          accI[mi][ni] = __builtin_amdgcn_mfma_f32_16x16x32_bf16(
              a[mi], b2[ni], accI[mi][ni], 0, 0, 0);
      __builtin_amdgcn_sched_barrier(0);
    }
  }

  full_drain();
  __syncthreads();
#pragma unroll
  for (int mi = 0; mi < 4; ++mi)
#pragma unroll
    for (int ni = 0; ni < 3; ++ni) {
      int col = wc * 48 + ni * 16 + lr;
      float bb = bbiv[n0 + col];
#pragma unroll
      for (int r = 0; r < 4; ++r) {
        int row = wr * 64 + mi * 16 + lk * 4 + r;
        sBv[row * 97 + col] = accB[mi][ni][r] + bb;
      }
    }
  full_drain();
  __syncthreads();

#pragma unroll
  for (int mi = 0; mi < 4; ++mi)
#pragma unroll
    for (int ni = 0; ni < 3; ++ni) {
      int col  = wc * 48 + ni * 16 + lr;
      int gcol = n0 + col;
      int c    = (col % 3);
      int lc0  = col - c;
      float binv = bin[gcol];
#pragma unroll
      for (int r = 0; r < 4; ++r) {
        int row  = wr * 64 + mi * 16 + lk * 4 + r;
        int grow = m0 + row;
        float bx = sBv[row * 97 + lc0];
        float by = sBv[row * 97 + lc0 + 1];
        float bz = sBv[row * 97 + lc0 + 2];
        const float* hp = hprev + (long)grow * D_MODEL + (n0 + lc0);
        float vx = hp[0], vy = hp[1], vz = hp[2];
        float nb = sqrtf(bx * bx + by * by + bz * bz);
        nb = fmaxf(nb, EPS);
        float ha = 0.5f * nb;
        float w  = cosf(ha);
        float s  = sinf(ha) / nb;
        float qx = s * bz, qy = -s * by, qz = s * bx;
        float tx = 2.f * (qy * vz - qz * vy);
        float ty = 2.f * (qz * vx - qx * vz);
        float tz = 2.f * (qx * vy - qy * vx);
        float rx = vx + w * tx + (qy * tz - qz * ty);
        float ry = vy + w * ty + (qz * tx - qx * tz);
        float rz = vz + w * tz + (qx * ty - qy * tx);
        float rc = (c == 0) ? rx : ((c == 1) ? ry : rz);
        out[(long)grow * D_MODEL + gcol] =
            sDecay[row] * rc + (accI[mi][ni][r] + binv);
      }
    }
}

// -------------------------------------------------------------------------
extern "C" void kernel_launch(void* const* d_in, const int* in_sizes, int n_in,
                              void* d_out, int out_size, void* d_ws, size_t ws_size,
                              hipStream_t stream) {
  const float* x     = (const float*)d_in[0];
  const float* hprev = (const float*)d_in[1];
  const float* wbiv  = (const float*)d_in[2];
  const float* bbiv  = (const float*)d_in[3];
  const float* wdec  = (const float*)d_in[4];
  const float* bdec  = (const float*)d_in[5];
  const float* win   = (const float*)d_in[6];
  const float* bin   = (const float*)d_in[7];
  float* out = (float*)d_out;

  const size_t XB_B  = 25165824;   // 8192*1536*2
  const size_t WB_B  = 9437184;    // 2*1536*1536*2
  const size_t DC_B  = 32768;      // 8192*4

  if (ws_size >= XB_B + WB_B + DC_B) {
    char* ws = (char*)d_ws;
    unsigned short* xb = (unsigned short*)ws;
    unsigned short* wb = (unsigned short*)(ws + XB_B);
    float* decay       = (float*)(ws + XB_B + WB_B);
    prep_kernel<<<dim3(2048), dim3(256), 0, stream>>>(x, wbiv, win, xb, wb);
    decay_kernel<<<dim3(2048), dim3(256), 0, stream>>>(x, wdec, bdec, decay);
    fused_main<<<dim3(NTM * NTN), dim3(512), 0, stream>>>(
        xb, wb, hprev, decay, bbiv, bin, out);
  } else {
    fused_mfma3<<<dim3(NTM * NTN), dim3(256), 0, stream>>>(
        x, wbiv, win, hprev, wdec, bdec, bbiv, bin, out);
  }
}

// Round 14
// 125.967 us; speedup vs baseline: 1.4955x; 1.4955x over previous
//
#include <hip/hip_runtime.h>
#include <cstdint>

#define D_MODEL 1536
#define BATCH   8192
#define EPS     1e-8f

#define BM 128
#define BN 96        // multiple of 3: quaternion blocks never straddle a tile
#define BK 64
#define NTN (D_MODEL / BN)   // 16
#define NTM (BATCH / BM)     // 64

typedef __attribute__((ext_vector_type(8))) short bf16x8;
typedef __attribute__((ext_vector_type(8))) unsigned short ushort8;
typedef __attribute__((ext_vector_type(4))) float f32x4;

__device__ __forceinline__ unsigned short f2bf(float f) {
  unsigned u = __builtin_bit_cast(unsigned, f);
  u += 0x7fffu + ((u >> 16) & 1u);            // round-to-nearest-even
  return (unsigned short)(u >> 16);
}

__device__ __forceinline__ ushort8 pack8u(float4 a, float4 b) {
  ushort8 o;
  o[0] = f2bf(a.x); o[1] = f2bf(a.y); o[2] = f2bf(a.z); o[3] = f2bf(a.w);
  o[4] = f2bf(b.x); o[5] = f2bf(b.y); o[6] = f2bf(b.z); o[7] = f2bf(b.w);
  return o;
}

__device__ __forceinline__ void full_drain() {
  asm volatile("s_waitcnt vmcnt(0) lgkmcnt(0)" ::: "memory");
}

__device__ __forceinline__ void load_lds16(const void* g, void* l) {
  __builtin_amdgcn_global_load_lds(
      (const __attribute__((address_space(1))) unsigned int*)g,
      (__attribute__((address_space(3))) unsigned int*)l,
      16, 0, 0);
}

// ---------------- prep_xd: x f32->bf16 AND decay, one x read -------------
// One wave per row: convert the row to bf16 and fold in the w_dec dot.
__global__ void prep_xd(const float* __restrict__ x,
                        const float* __restrict__ wdec,
                        const float* __restrict__ bdec,
                        unsigned short* __restrict__ xb,
                        float* __restrict__ decay) {
  int row  = (int)((blockIdx.x * blockDim.x + threadIdx.x) >> 6);
  int lane = threadIdx.x & 63;
  if (row >= BATCH) return;
  const float4* xr = (const float4*)(x + (long)row * D_MODEL);
  const float4* wr = (const float4*)wdec;
  unsigned short* xo = xb + (long)row * D_MODEL;
  float acc = 0.f;
#pragma unroll
  for (int i = 0; i < 6; ++i) {                // 6*64*4 = 1536
    float4 a = xr[lane + 64 * i];
    float4 b = wr[lane + 64 * i];
    acc += a.x * b.x + a.y * b.y + a.z * b.z + a.w * b.w;
    ushort4 o;
    o.x = f2bf(a.x); o.y = f2bf(a.y); o.z = f2bf(a.z); o.w = f2bf(a.w);
    *(ushort4*)(xo + (lane + 64 * i) * 4) = o;
  }
  for (int off = 32; off; off >>= 1) acc += __shfl_xor(acc, off);
  if (lane == 0) decay[row] = 1.f / (1.f + expf(-(acc + bdec[0])));
}

// ---------------- prep_w: f32 -> bf16 for W_biv, W_in --------------------
__global__ void prep_w(const float* __restrict__ wbiv,
                       const float* __restrict__ win,
                       unsigned short* __restrict__ wb) {
  const long NW4 = (long)D_MODEL * D_MODEL / 4;   // 589824 float4s per matrix
  for (long i = (long)blockIdx.x * blockDim.x + threadIdx.x; i < 2 * NW4;
       i += (long)gridDim.x * blockDim.x) {
    const float4* src = (i < NW4) ? (const float4*)wbiv : (const float4*)win;
    long j = (i < NW4) ? i : (i - NW4);
    float4 v = src[j];
    ushort4 o;
    o.x = f2bf(v.x); o.y = f2bf(v.y); o.z = f2bf(v.z); o.w = f2bf(v.w);
    *(ushort4*)(wb + 4 * i) = o;     // W_in lands at wb + D_MODEL*D_MODEL
  }
}

// ---------------- main: dual-GEMM + quaternion epilogue (r11 verbatim) ----
// 512 threads / 8 waves (4x2 grid, 32x48 per wave). Two fence regions per
// K-tile (per-ks). This exact structure measured 134 us total (r11).
__global__ __launch_bounds__(512, 2)
void fused_main(const unsigned short* __restrict__ xb,
                const unsigned short* __restrict__ wb,
                const float* __restrict__ hprev,
                const float* __restrict__ decay,
                const float* __restrict__ bbiv,
                const float* __restrict__ bin,
                float* __restrict__ out) {
  __shared__ __align__(16) char smem[50688];
  __shared__ float sDecay[BM];
  unsigned short* sA  = (unsigned short*)smem;             // [128][64] bf16
  unsigned short* sB1 = (unsigned short*)(smem + 16384);   // [96][64]
  unsigned short* sB2 = (unsigned short*)(smem + 28672);   // [96][64]
  float* sBv = (float*)smem;                               // [128][97] overlay

  const int bid = blockIdx.x;
  const int tm = bid / NTN, tn = bid % NTN;
  const int m0 = tm * BM, n0 = tn * BN;
  const int tid  = threadIdx.x;
  const int lane = tid & 63, wid = tid >> 6;
  const int wr = wid >> 1, wc = wid & 1;   // 4x2 wave grid: 32x48 per wave
  const int lr = lane & 15;                // fragment row/col
  const int lk = lane >> 4;                // k-octet group

  if (tid < BM) sDecay[tid] = decay[m0 + tid];   // published by first barrier

  // acc*[mi][ni][r] == C[wr*32+mi*16+lk*4+r][n0+wc*48+ni*16+lr]
  f32x4 accB[2][3], accI[2][3];
#pragma unroll
  for (int a = 0; a < 2; ++a)
#pragma unroll
    for (int b = 0; b < 3; ++b) { accB[a][b] = (f32x4)0.f; accI[a][b] = (f32x4)0.f; }

  for (int kt = 0; kt < D_MODEL; kt += BK) {
    full_drain();
    __syncthreads();
    // ---- stage A (128x64 bf16): linear LDS dest, source slot swizzled ----
#pragma unroll
    for (int i = 0; i < 2; ++i) {
      int f = i * 512 + tid;               // [0,1024)
      int row = f >> 3, c = f & 7;
      int cs = c ^ (row & 7);              // inverse-swizzled source slot
      const unsigned short* g = xb + (long)(m0 + row) * D_MODEL + kt + cs * 8;
      load_lds16(g, smem + ((i * 512 + wid * 64) << 4));
    }
    // ---- stage B1 = W_biv rows (768 chunks) ----
    {
      int f = tid;
      int row = f >> 3, c = f & 7, cs = c ^ (row & 7);
      const unsigned short* g = wb + (long)(n0 + row) * D_MODEL + kt + cs * 8;
      load_lds16(g, smem + 16384 + ((wid * 64) << 4));
    }
    if (tid < 256) {
      int f = 512 + tid;
      int row = f >> 3, c = f & 7, cs = c ^ (row & 7);
      const unsigned short* g = wb + (long)(n0 + row) * D_MODEL + kt + cs * 8;
      load_lds16(g, smem + 16384 + ((512 + wid * 64) << 4));
    }
    // ---- stage B2 = W_in rows (768 chunks) ----
    {
      int f = tid;
      int row = f >> 3, c = f & 7, cs = c ^ (row & 7);
      const unsigned short* g = wb + (long)(D_MODEL + n0 + row) * D_MODEL + kt + cs * 8;
      load_lds16(g, smem + 28672 + ((wid * 64) << 4));
    }
    if (tid < 256) {
      int f = 512 + tid;
      int row = f >> 3, c = f & 7, cs = c ^ (row & 7);
      const unsigned short* g = wb + (long)(D_MODEL + n0 + row) * D_MODEL + kt + cs * 8;
      load_lds16(g, smem + 28672 + ((512 + wid * 64) << 4));
    }
    full_drain();                          // global_load_lds data landed
    __syncthreads();

    // ---- MFMA core (r11 fence pattern), swizzled ds_read slots ----
#pragma unroll
    for (int ks = 0; ks < 2; ++ks) {
      const int slot = ks * 4 + lk;        // logical k-octet slot (0..7)
      bf16x8 a[2], b1[3], b2[3];
#pragma unroll
      for (int mi = 0; mi < 2; ++mi) {
        int R = wr * 32 + mi * 16 + lr;
        a[mi] = *(const bf16x8*)(sA + R * 64 + (slot ^ (R & 7)) * 8);
      }
#pragma unroll
      for (int ni = 0; ni < 3; ++ni) {
        int R = wc * 48 + ni * 16 + lr;
        b1[ni] = *(const bf16x8*)(sB1 + R * 64 + (slot ^ (R & 7)) * 8);
        b2[ni] = *(const bf16x8*)(sB2 + R * 64 + (slot ^ (R & 7)) * 8);
      }
      full_drain();                          // all LDS reads complete
      __builtin_amdgcn_sched_barrier(0);     // operands finalized before MFMAs
#pragma unroll
      for (int mi = 0; mi < 2; ++mi)
#pragma unroll
        for (int ni = 0; ni < 3; ++ni)
          accB[mi][ni] = __builtin_amdgcn_mfma_f32_16x16x32_bf16(
              a[mi], b1[ni], accB[mi][ni], 0, 0, 0);
      __builtin_amdgcn_sched_barrier(0);     // no chain interleave
#pragma unroll
      for (int mi = 0; mi < 2; ++mi)
#pragma unroll
        for (int ni = 0; ni < 3; ++ni)
          accI[mi][ni] = __builtin_amdgcn_mfma_f32_16x16x32_bf16(
              a[mi], b2[ni], accI[mi][ni], 0, 0, 0);
      __builtin_amdgcn_sched_barrier(0);
    }
  }

  // ---- epilogue (green r11 logic) ----
  full_drain();
  __syncthreads();
#pragma unroll
  for (int mi = 0; mi < 2; ++mi)
#pragma unroll
    for (int ni = 0; ni < 3; ++ni) {
      int col = wc * 48 + ni * 16 + lr;
      float bb = bbiv[n0 + col];
#pragma unroll
      for (int r = 0; r < 4; ++r) {
        int row = wr * 32 + mi * 16 + lk * 4 + r;
        sBv[row * 97 + col] = accB[mi][ni][r] + bb;
      }
    }
  full_drain();
  __syncthreads();

#pragma unroll
  for (int mi = 0; mi < 2; ++mi)
#pragma unroll
    for (int ni = 0; ni < 3; ++ni) {
      int col  = wc * 48 + ni * 16 + lr;
      int gcol = n0 + col;
      int c    = (col % 3);        // n0 % 3 == 0
      int lc0  = col - c;
      float binv = bin[gcol];
#pragma unroll
      for (int r = 0; r < 4; ++r) {
        int row  = wr * 32 + mi * 16 + lk * 4 + r;
        int grow = m0 + row;
        float bx = sBv[row * 97 + lc0];
        float by = sBv[row * 97 + lc0 + 1];
        float bz = sBv[row * 97 + lc0 + 2];
        const float* hp = hprev + (long)grow * D_MODEL + (n0 + lc0);
        float vx = hp[0], vy = hp[1], vz = hp[2];
        float nb = sqrtf(bx * bx + by * by + bz * bz);
        nb = fmaxf(nb, EPS);
        float ha = 0.5f * nb;
        float w  = cosf(ha);
        float s  = sinf(ha) / nb;
        // faithful to reference quirk: qx from bz, qy from -by, qz from bx
        float qx = s * bz, qy = -s * by, qz = s * bx;
        float tx = 2.f * (qy * vz - qz * vy);
        float ty = 2.f * (qz * vx - qx * vz);
        float tz = 2.f * (qx * vy - qy * vx);
        float rx = vx + w * tx + (qy * tz - qz * ty);
        float ry = vy + w * ty + (qz * tx - qx * tz);
        float rz = vz + w * tz + (qx * ty - qy * tx);
        float rc = (c == 0) ? rx : ((c == 1) ? ry : rz);
        out[(long)grow * D_MODEL + gcol] =
            sDecay[row] * rc + (accI[mi][ni][r] + binv);
      }
    }
}

// ---------------- fallback (r7 green kernel, hammers retained) ------------
__global__ __launch_bounds__(256, 2)
void fused_mfma3(const float* __restrict__ x,
                 const float* __restrict__ wbiv,
                 const float* __restrict__ win,
                 const float* __restrict__ hprev,
                 const float* __restrict__ wdec,
                 const float* __restrict__ bdec,
                 const float* __restrict__ bbiv,
                 const float* __restrict__ bin,
                 float* __restrict__ out) {
  __shared__ __align__(16) char smem[50688];
  __shared__ float sDecay[BM];
  unsigned short* sA  = (unsigned short*)smem;
  unsigned short* sB1 = (unsigned short*)(smem + 16384);
  unsigned short* sB2 = (unsigned short*)(smem + 28672);
  float* sBv = (float*)smem;

  const int bid = blockIdx.x;
  const int tm = bid / NTN, tn = bid % NTN;
  const int m0 = tm * BM, n0 = tn * BN;
  const int tid  = threadIdx.x;
  const int lane = tid & 63, wid = tid >> 6;
  const int wr = wid >> 1, wc = wid & 1;
  const int lr = lane & 15;
  const int lk = lane >> 4;

  {
    const float bd = bdec[0];
    const float4* wd4 = (const float4*)wdec;
    for (int rr = 0; rr < 32; ++rr) {
      int row = wid * 32 + rr;
      const float4* xr = (const float4*)(x + (long)(m0 + row) * D_MODEL);
      float acc = 0.f;
#pragma unroll
      for (int i = 0; i < 6; ++i) {
        float4 a = xr[lane + 64 * i];
        float4 b = wd4[lane + 64 * i];
        acc += a.x * b.x + a.y * b.y + a.z * b.z + a.w * b.w;
      }
      for (int off = 32; off; off >>= 1) acc += __shfl_xor(acc, off);
      if (lane == 0) sDecay[row] = 1.f / (1.f + expf(-(acc + bd)));
    }
  }

  f32x4 accB[4][3], accI[4][3];
#pragma unroll
  for (int a = 0; a < 4; ++a)
#pragma unroll
    for (int b = 0; b < 3; ++b) { accB[a][b] = (f32x4)0.f; accI[a][b] = (f32x4)0.f; }

  for (int kt = 0; kt < D_MODEL; kt += BK) {
    full_drain();
    __syncthreads();
#pragma unroll
    for (int i = 0; i < 4; ++i) {
      int f = i * 256 + tid;
      int row = f >> 3, c = f & 7;
      const float4* p = (const float4*)(x + (long)(m0 + row) * D_MODEL + kt + c * 8);
      *(ushort8*)(sA + row * 64 + c * 8) = pack8u(p[0], p[1]);
    }
#pragma unroll
    for (int i = 0; i < 6; ++i) {
      int mat = (i >= 3);
      int g = (i - 3 * mat) * 256 + tid;
      int row = g >> 3, c = g & 7;
      const float* wsrc = mat ? win : wbiv;
      const float4* p = (const float4*)(wsrc + (long)(n0 + row) * D_MODEL + kt + c * 8);
      *(ushort8*)((mat ? sB2 : sB1) + row * 64 + c * 8) = pack8u(p[0], p[1]);
    }
    full_drain();
    __syncthreads();

#pragma unroll
    for (int ks = 0; ks < 2; ++ks) {
      const int k0 = ks * 32 + lk * 8;
      bf16x8 a[4], b1[3], b2[3];
#pragma unroll
      for (int mi = 0; mi < 4; ++mi)
        a[mi] = *(const bf16x8*)(sA + (wr * 64 + mi * 16 + lr) * 64 + k0);
#pragma unroll
      for (int ni = 0; ni < 3; ++ni) {
        b1[ni] = *(const bf16x8*)(sB1 + (wc * 48 + ni * 16 + lr) * 64 + k0);
        b2[ni] = *(const bf16x8*)(sB2 + (wc * 48 + ni * 16 + lr) * 64 + k0);
      }
      full_drain();
      __builtin_amdgcn_sched_barrier(0);
#pragma unroll
      for (int mi = 0; mi < 4; ++mi)
#pragma unroll
        for (int ni = 0; ni < 3; ++ni)
          accB[mi][ni] = __builtin_amdgcn_mfma_f32_16x16x32_bf16(
              a[mi], b1[ni], accB[mi][ni], 0, 0, 0);
      __builtin_amdgcn_sched_barrier(0);
#pragma unroll
      for (int mi = 0; mi < 4; ++mi)
#pragma unroll
        for (int ni = 0; ni < 3; ++ni)
          accI[mi][ni] = __builtin_amdgcn_mfma_f32_16x16x32_bf16(
              a[mi], b2[ni], accI[mi][ni], 0, 0, 0);
      __builtin_amdgcn_sched_barrier(0);
    }
  }

  full_drain();
  __syncthreads();
#pragma unroll
  for (int mi = 0; mi < 4; ++mi)
#pragma unroll
    for (int ni = 0; ni < 3; ++ni) {
      int col = wc * 48 + ni * 16 + lr;
      float bb = bbiv[n0 + col];
#pragma unroll
      for (int r = 0; r < 4; ++r) {
        int row = wr * 64 + mi * 16 + lk * 4 + r;
        sBv[row * 97 + col] = accB[mi][ni][r] + bb;
      }
    }
  full_drain();
  __syncthreads();

#pragma unroll
  for (int mi = 0; mi < 4; ++mi)
#pragma unroll
    for (int ni = 0; ni < 3; ++ni) {
      int col  = wc * 48 + ni * 16 + lr;
      int gcol = n0 + col;
      int c    = (col % 3);
      int lc0  = col - c;
      float binv = bin[gcol];
#pragma unroll
      for (int r = 0; r < 4; ++r) {
        int row  = wr * 64 + mi * 16 + lk * 4 + r;
        int grow = m0 + row;
        float bx = sBv[row * 97 + lc0];
        float by = sBv[row * 97 + lc0 + 1];
        float bz = sBv[row * 97 + lc0 + 2];
        const float* hp = hprev + (long)grow * D_MODEL + (n0 + lc0);
        float vx = hp[0], vy = hp[1], vz = hp[2];
        float nb = sqrtf(bx * bx + by * by + bz * bz);
        nb = fmaxf(nb, EPS);
        float ha = 0.5f * nb;
        float w  = cosf(ha);
        float s  = sinf(ha) / nb;
        float qx = s * bz, qy = -s * by, qz = s * bx;
        float tx = 2.f * (qy * vz - qz * vy);
        float ty = 2.f * (qz * vx - qx * vz);
        float tz = 2.f * (qx * vy - qy * vx);
        float rx = vx + w * tx + (qy * tz - qz * ty);
        float ry = vy + w * ty + (qz * tx - qx * tz);
        float rz = vz + w * tz + (qx * ty - qy * tx);
        float rc = (c == 0) ? rx : ((c == 1) ? ry : rz);
        out[(long)grow * D_MODEL + gcol] =
            sDecay[row] * rc + (accI[mi][ni][r] + binv);
      }
    }
}

// -------------------------------------------------------------------------
extern "C" void kernel_launch(void* const* d_in, const int* in_sizes, int n_in,
                              void* d_out, int out_size, void* d_ws, size_t ws_size,
                              hipStream_t stream) {
  const float* x     = (const float*)d_in[0];
  const float* hprev = (const float*)d_in[1];
  const float* wbiv  = (const float*)d_in[2];
  const float* bbiv  = (const float*)d_in[3];
  const float* wdec  = (const float*)d_in[4];
  const float* bdec  = (const float*)d_in[5];
  const float* win   = (const float*)d_in[6];
  const float* bin   = (const float*)d_in[7];
  float* out = (float*)d_out;

  const size_t XB_B  = 25165824;   // 8192*1536*2
  const size_t WB_B  = 9437184;    // 2*1536*1536*2
  const size_t DC_B  = 32768;      // 8192*4

  if (ws_size >= XB_B + WB_B + DC_B) {
    char* ws = (char*)d_ws;
    unsigned short* xb = (unsigned short*)ws;
    unsigned short* wb = (unsigned short*)(ws + XB_B);
    float* decay       = (float*)(ws + XB_B + WB_B);
    prep_xd<<<dim3(2048), dim3(256), 0, stream>>>(x, wdec, bdec, xb, decay);
    prep_w<<<dim3(1024), dim3(256), 0, stream>>>(wbiv, win, wb);
    fused_main<<<dim3(NTM * NTN), dim3(512), 0, stream>>>(
        xb, wb, hprev, decay, bbiv, bin, out);
  } else {
    fused_mfma3<<<dim3(NTM * NTN), dim3(256), 0, stream>>>(
        x, wbiv, win, hprev, wdec, bdec, bbiv, bin, out);
  }
}

// Round 15
// 125.208 us; speedup vs baseline: 1.5046x; 1.0061x over previous
//
#include <hip/hip_runtime.h>
#include <cstdint>

#define D_MODEL 1536
#define BATCH   8192
#define EPS     1e-8f

#define BM 128
#define BN 96        // multiple of 3: quaternion blocks never straddle a tile
#define BK 64
#define NT (D_MODEL / BK)    // 24 K-tiles
#define NTN (D_MODEL / BN)   // 16
#define NTM (BATCH / BM)     // 64
#define BUF 40960            // bytes per LDS buffer (A 16384 + B1 12288 + B2 12288)

typedef __attribute__((ext_vector_type(8))) short bf16x8;
typedef __attribute__((ext_vector_type(8))) unsigned short ushort8;
typedef __attribute__((ext_vector_type(4))) float f32x4;

__device__ __forceinline__ unsigned short f2bf(float f) {
  unsigned u = __builtin_bit_cast(unsigned, f);
  u += 0x7fffu + ((u >> 16) & 1u);            // round-to-nearest-even
  return (unsigned short)(u >> 16);
}

__device__ __forceinline__ ushort8 pack8u(float4 a, float4 b) {
  ushort8 o;
  o[0] = f2bf(a.x); o[1] = f2bf(a.y); o[2] = f2bf(a.z); o[3] = f2bf(a.w);
  o[4] = f2bf(b.x); o[5] = f2bf(b.y); o[6] = f2bf(b.z); o[7] = f2bf(b.w);
  return o;
}

__device__ __forceinline__ void full_drain() {
  asm volatile("s_waitcnt vmcnt(0) lgkmcnt(0)" ::: "memory");
}
__device__ __forceinline__ void vm_drain() {
  asm volatile("s_waitcnt vmcnt(0)" ::: "memory");
}
__device__ __forceinline__ void lgkm_drain() {
  asm volatile("s_waitcnt lgkmcnt(0)" ::: "memory");
}

__device__ __forceinline__ void load_lds16(const void* g, void* l) {
  __builtin_amdgcn_global_load_lds(
      (const __attribute__((address_space(1))) unsigned int*)g,
      (__attribute__((address_space(3))) unsigned int*)l,
      16, 0, 0);
}

// ---------------- prep_xd: x f32->bf16 AND decay, one x read -------------
__global__ void prep_xd(const float* __restrict__ x,
                        const float* __restrict__ wdec,
                        const float* __restrict__ bdec,
                        unsigned short* __restrict__ xb,
                        float* __restrict__ decay) {
  int row  = (int)((blockIdx.x * blockDim.x + threadIdx.x) >> 6);
  int lane = threadIdx.x & 63;
  if (row >= BATCH) return;
  const float4* xr = (const float4*)(x + (long)row * D_MODEL);
  const float4* wr = (const float4*)wdec;
  unsigned short* xo = xb + (long)row * D_MODEL;
  float acc = 0.f;
#pragma unroll
  for (int i = 0; i < 6; ++i) {                // 6*64*4 = 1536
    float4 a = xr[lane + 64 * i];
    float4 b = wr[lane + 64 * i];
    acc += a.x * b.x + a.y * b.y + a.z * b.z + a.w * b.w;
    ushort4 o;
    o.x = f2bf(a.x); o.y = f2bf(a.y); o.z = f2bf(a.z); o.w = f2bf(a.w);
    *(ushort4*)(xo + (lane + 64 * i) * 4) = o;
  }
  for (int off = 32; off; off >>= 1) acc += __shfl_xor(acc, off);
  if (lane == 0) decay[row] = 1.f / (1.f + expf(-(acc + bdec[0])));
}

// ---------------- prep_w: f32 -> bf16 for W_biv, W_in --------------------
__global__ void prep_w(const float* __restrict__ wbiv,
                       const float* __restrict__ win,
                       unsigned short* __restrict__ wb) {
  const long NW4 = (long)D_MODEL * D_MODEL / 4;
  for (long i = (long)blockIdx.x * blockDim.x + threadIdx.x; i < 2 * NW4;
       i += (long)gridDim.x * blockDim.x) {
    const float4* src = (i < NW4) ? (const float4*)wbiv : (const float4*)win;
    long j = (i < NW4) ? i : (i - NW4);
    float4 v = src[j];
    ushort4 o;
    o.x = f2bf(v.x); o.y = f2bf(v.y); o.z = f2bf(v.z); o.w = f2bf(v.w);
    *(ushort4*)(wb + 4 * i) = o;
  }
}

// ---------------- main: dual-GEMM + quaternion epilogue -------------------
// r14 structure + T3 2-phase double-buffer: STAGE(t+1) issued BEFORE compute(t);
// vmcnt(0) drained only at iteration-end barrier. MFMA hammers unchanged:
// ds_read -> lgkmcnt(0) -> sched_barrier(0) -> MFMA chain -> sched_barrier(0).
__global__ __launch_bounds__(512, 2)
void fused_main(const unsigned short* __restrict__ xb,
                const unsigned short* __restrict__ wb,
                const float* __restrict__ hprev,
                const float* __restrict__ decay,
                const float* __restrict__ bbiv,
                const float* __restrict__ bin,
                float* __restrict__ out) {
  __shared__ __align__(16) char smem[2 * BUF];   // 81920 B -> 2 blocks/CU
  float* sBv = (float*)smem;                     // [128][97] epilogue overlay

  const int bid = blockIdx.x;
  const int tm = bid / NTN, tn = bid % NTN;
  const int m0 = tm * BM, n0 = tn * BN;
  const int tid  = threadIdx.x;
  const int lane = tid & 63, wid = tid >> 6;
  const int wr = wid >> 1, wc = wid & 1;   // 4x2 wave grid: 32x48 per wave
  const int lr = lane & 15;                // fragment row/col
  const int lk = lane >> 4;                // k-octet group

  // acc*[mi][ni][r] == C[wr*32+mi*16+lk*4+r][n0+wc*48+ni*16+lr]
  f32x4 accB[2][3], accI[2][3];
#pragma unroll
  for (int a = 0; a < 2; ++a)
#pragma unroll
    for (int b = 0; b < 3; ++b) { accB[a][b] = (f32x4)0.f; accI[a][b] = (f32x4)0.f; }

  // stage tile `kt` (element offset) into buffer at byte offset bb
  auto STAGE = [&](int kt, int bb) {
#pragma unroll
    for (int i = 0; i < 2; ++i) {
      int f = i * 512 + tid;               // [0,1024)
      int row = f >> 3, c = f & 7;
      int cs = c ^ (row & 7);              // inverse-swizzled source slot
      const unsigned short* g = xb + (long)(m0 + row) * D_MODEL + kt + cs * 8;
      load_lds16(g, smem + bb + ((i * 512 + wid * 64) << 4));
    }
    {
      int f = tid;
      int row = f >> 3, c = f & 7, cs = c ^ (row & 7);
      const unsigned short* g = wb + (long)(n0 + row) * D_MODEL + kt + cs * 8;
      load_lds16(g, smem + bb + 16384 + ((wid * 64) << 4));
    }
    if (tid < 256) {
      int f = 512 + tid;
      int row = f >> 3, c = f & 7, cs = c ^ (row & 7);
      const unsigned short* g = wb + (long)(n0 + row) * D_MODEL + kt + cs * 8;
      load_lds16(g, smem + bb + 16384 + ((512 + wid * 64) << 4));
    }
    {
      int f = tid;
      int row = f >> 3, c = f & 7, cs = c ^ (row & 7);
      const unsigned short* g = wb + (long)(D_MODEL + n0 + row) * D_MODEL + kt + cs * 8;
      load_lds16(g, smem + bb + 28672 + ((wid * 64) << 4));
    }
    if (tid < 256) {
      int f = 512 + tid;
      int row = f >> 3, c = f & 7, cs = c ^ (row & 7);
      const unsigned short* g = wb + (long)(D_MODEL + n0 + row) * D_MODEL + kt + cs * 8;
      load_lds16(g, smem + bb + 28672 + ((512 + wid * 64) << 4));
    }
  };

  // prologue: fill buffer 0
  STAGE(0, 0);
  vm_drain();
  __syncthreads();

  for (int t = 0; t < NT; ++t) {
    const int cur = (t & 1) * BUF;
    if (t + 1 < NT) STAGE((t + 1) * BK, ((t + 1) & 1) * BUF);   // prefetch

    const unsigned short* cA  = (const unsigned short*)(smem + cur);
    const unsigned short* cB1 = (const unsigned short*)(smem + cur + 16384);
    const unsigned short* cB2 = (const unsigned short*)(smem + cur + 28672);

#pragma unroll
    for (int ks = 0; ks < 2; ++ks) {
      const int slot = ks * 4 + lk;        // logical k-octet slot (0..7)
      bf16x8 a[2], b1[3], b2[3];
#pragma unroll
      for (int mi = 0; mi < 2; ++mi) {
        int R = wr * 32 + mi * 16 + lr;
        a[mi] = *(const bf16x8*)(cA + R * 64 + (slot ^ (R & 7)) * 8);
      }
#pragma unroll
      for (int ni = 0; ni < 3; ++ni) {
        int R = wc * 48 + ni * 16 + lr;
        b1[ni] = *(const bf16x8*)(cB1 + R * 64 + (slot ^ (R & 7)) * 8);
        b2[ni] = *(const bf16x8*)(cB2 + R * 64 + (slot ^ (R & 7)) * 8);
      }
      lgkm_drain();                          // operands in registers
      __builtin_amdgcn_sched_barrier(0);     // no reorder into MFMA chain
#pragma unroll
      for (int mi = 0; mi < 2; ++mi)
#pragma unroll
        for (int ni = 0; ni < 3; ++ni)
          accB[mi][ni] = __builtin_amdgcn_mfma_f32_16x16x32_bf16(
              a[mi], b1[ni], accB[mi][ni], 0, 0, 0);
      __builtin_amdgcn_sched_barrier(0);     // no chain interleave
#pragma unroll
      for (int mi = 0; mi < 2; ++mi)
#pragma unroll
        for (int ni = 0; ni < 3; ++ni)
          accI[mi][ni] = __builtin_amdgcn_mfma_f32_16x16x32_bf16(
              a[mi], b2[ni], accI[mi][ni], 0, 0, 0);
      __builtin_amdgcn_sched_barrier(0);
    }

    vm_drain();        // prefetched tile landed; all LDS reads already drained
    __syncthreads();   // safe to overwrite buffer (t&1) next iteration
  }

  // ---- epilogue (r14 logic; decay read direct from L2-resident array) ----
#pragma unroll
  for (int mi = 0; mi < 2; ++mi)
#pragma unroll
    for (int ni = 0; ni < 3; ++ni) {
      int col = wc * 48 + ni * 16 + lr;
      float bb = bbiv[n0 + col];
#pragma unroll
      for (int r = 0; r < 4; ++r) {
        int row = wr * 32 + mi * 16 + lk * 4 + r;
        sBv[row * 97 + col] = accB[mi][ni][r] + bb;
      }
    }
  full_drain();
  __syncthreads();

#pragma unroll
  for (int mi = 0; mi < 2; ++mi)
#pragma unroll
    for (int ni = 0; ni < 3; ++ni) {
      int col  = wc * 48 + ni * 16 + lr;
      int gcol = n0 + col;
      int c    = (col % 3);        // n0 % 3 == 0
      int lc0  = col - c;
      float binv = bin[gcol];
#pragma unroll
      for (int r = 0; r < 4; ++r) {
        int row  = wr * 32 + mi * 16 + lk * 4 + r;
        int grow = m0 + row;
        float bx = sBv[row * 97 + lc0];
        float by = sBv[row * 97 + lc0 + 1];
        float bz = sBv[row * 97 + lc0 + 2];
        const float* hp = hprev + (long)grow * D_MODEL + (n0 + lc0);
        float vx = hp[0], vy = hp[1], vz = hp[2];
        float nb = sqrtf(bx * bx + by * by + bz * bz);
        nb = fmaxf(nb, EPS);
        float ha = 0.5f * nb;
        float w  = cosf(ha);
        float s  = sinf(ha) / nb;
        // faithful to reference quirk: qx from bz, qy from -by, qz from bx
        float qx = s * bz, qy = -s * by, qz = s * bx;
        float tx = 2.f * (qy * vz - qz * vy);
        float ty = 2.f * (qz * vx - qx * vz);
        float tz = 2.f * (qx * vy - qy * vx);
        float rx = vx + w * tx + (qy * tz - qz * ty);
        float ry = vy + w * ty + (qz * tx - qx * tz);
        float rz = vz + w * tz + (qx * ty - qy * tx);
        float rc = (c == 0) ? rx : ((c == 1) ? ry : rz);
        out[(long)grow * D_MODEL + gcol] =
            decay[grow] * rc + (accI[mi][ni][r] + binv);
      }
    }
}

// ---------------- fallback (r7 green kernel, hammers retained) ------------
__global__ __launch_bounds__(256, 2)
void fused_mfma3(const float* __restrict__ x,
                 const float* __restrict__ wbiv,
                 const float* __restrict__ win,
                 const float* __restrict__ hprev,
                 const float* __restrict__ wdec,
                 const float* __restrict__ bdec,
                 const float* __restrict__ bbiv,
                 const float* __restrict__ bin,
                 float* __restrict__ out) {
  __shared__ __align__(16) char smem[50688];
  __shared__ float sDecay[BM];
  unsigned short* sA  = (unsigned short*)smem;
  unsigned short* sB1 = (unsigned short*)(smem + 16384);
  unsigned short* sB2 = (unsigned short*)(smem + 28672);
  float* sBv = (float*)smem;

  const int bid = blockIdx.x;
  const int tm = bid / NTN, tn = bid % NTN;
  const int m0 = tm * BM, n0 = tn * BN;
  const int tid  = threadIdx.x;
  const int lane = tid & 63, wid = tid >> 6;
  const int wr = wid >> 1, wc = wid & 1;
  const int lr = lane & 15;
  const int lk = lane >> 4;

  {
    const float bd = bdec[0];
    const float4* wd4 = (const float4*)wdec;
    for (int rr = 0; rr < 32; ++rr) {
      int row = wid * 32 + rr;
      const float4* xr = (const float4*)(x + (long)(m0 + row) * D_MODEL);
      float acc = 0.f;
#pragma unroll
      for (int i = 0; i < 6; ++i) {
        float4 a = xr[lane + 64 * i];
        float4 b = wd4[lane + 64 * i];
        acc += a.x * b.x + a.y * b.y + a.z * b.z + a.w * b.w;
      }
      for (int off = 32; off; off >>= 1) acc += __shfl_xor(acc, off);
      if (lane == 0) sDecay[row] = 1.f / (1.f + expf(-(acc + bd)));
    }
  }

  f32x4 accB[4][3], accI[4][3];
#pragma unroll
  for (int a = 0; a < 4; ++a)
#pragma unroll
    for (int b = 0; b < 3; ++b) { accB[a][b] = (f32x4)0.f; accI[a][b] = (f32x4)0.f; }

  for (int kt = 0; kt < D_MODEL; kt += BK) {
    full_drain();
    __syncthreads();
#pragma unroll
    for (int i = 0; i < 4; ++i) {
      int f = i * 256 + tid;
      int row = f >> 3, c = f & 7;
      const float4* p = (const float4*)(x + (long)(m0 + row) * D_MODEL + kt + c * 8);
      *(ushort8*)(sA + row * 64 + c * 8) = pack8u(p[0], p[1]);
    }
#pragma unroll
    for (int i = 0; i < 6; ++i) {
      int mat = (i >= 3);
      int g = (i - 3 * mat) * 256 + tid;
      int row = g >> 3, c = g & 7;
      const float* wsrc = mat ? win : wbiv;
      const float4* p = (const float4*)(wsrc + (long)(n0 + row) * D_MODEL + kt + c * 8);
      *(ushort8*)((mat ? sB2 : sB1) + row * 64 + c * 8) = pack8u(p[0], p[1]);
    }
    full_drain();
    __syncthreads();

#pragma unroll
    for (int ks = 0; ks < 2; ++ks) {
      const int k0 = ks * 32 + lk * 8;
      bf16x8 a[4], b1[3], b2[3];
#pragma unroll
      for (int mi = 0; mi < 4; ++mi)
        a[mi] = *(const bf16x8*)(sA + (wr * 64 + mi * 16 + lr) * 64 + k0);
#pragma unroll
      for (int ni = 0; ni < 3; ++ni) {
        b1[ni] = *(const bf16x8*)(sB1 + (wc * 48 + ni * 16 + lr) * 64 + k0);
        b2[ni] = *(const bf16x8*)(sB2 + (wc * 48 + ni * 16 + lr) * 64 + k0);
      }
      full_drain();
      __builtin_amdgcn_sched_barrier(0);
#pragma unroll
      for (int mi = 0; mi < 4; ++mi)
#pragma unroll
        for (int ni = 0; ni < 3; ++ni)
          accB[mi][ni] = __builtin_amdgcn_mfma_f32_16x16x32_bf16(
              a[mi], b1[ni], accB[mi][ni], 0, 0, 0);
      __builtin_amdgcn_sched_barrier(0);
#pragma unroll
      for (int mi = 0; mi < 4; ++mi)
#pragma unroll
        for (int ni = 0; ni < 3; ++ni)
          accI[mi][ni] = __builtin_amdgcn_mfma_f32_16x16x32_bf16(
              a[mi], b2[ni], accI[mi][ni], 0, 0, 0);
      __builtin_amdgcn_sched_barrier(0);
    }
  }

  full_drain();
  __syncthreads();
#pragma unroll
  for (int mi = 0; mi < 4; ++mi)
#pragma unroll
    for (int ni = 0; ni < 3; ++ni) {
      int col = wc * 48 + ni * 16 + lr;
      float bb = bbiv[n0 + col];
#pragma unroll
      for (int r = 0; r < 4; ++r) {
        int row = wr * 64 + mi * 16 + lk * 4 + r;
        sBv[row * 97 + col] = accB[mi][ni][r] + bb;
      }
    }
  full_drain();
  __syncthreads();

#pragma unroll
  for (int mi = 0; mi < 4; ++mi)
#pragma unroll
    for (int ni = 0; ni < 3; ++ni) {
      int col  = wc * 48 + ni * 16 + lr;
      int gcol = n0 + col;
      int c    = (col % 3);
      int lc0  = col - c;
      float binv = bin[gcol];
#pragma unroll
      for (int r = 0; r < 4; ++r) {
        int row  = wr * 64 + mi * 16 + lk * 4 + r;
        int grow = m0 + row;
        float bx = sBv[row * 97 + lc0];
        float by = sBv[row * 97 + lc0 + 1];
        float bz = sBv[row * 97 + lc0 + 2];
        const float* hp = hprev + (long)grow * D_MODEL + (n0 + lc0);
        float vx = hp[0], vy = hp[1], vz = hp[2];
        float nb = sqrtf(bx * bx + by * by + bz * bz);
        nb = fmaxf(nb, EPS);
        float ha = 0.5f * nb;
        float w  = cosf(ha);
        float s  = sinf(ha) / nb;
        float qx = s * bz, qy = -s * by, qz = s * bx;
        float tx = 2.f * (qy * vz - qz * vy);
        float ty = 2.f * (qz * vx - qx * vz);
        float tz = 2.f * (qx * vy - qy * vx);
        float rx = vx + w * tx + (qy * tz - qz * ty);
        float ry = vy + w * ty + (qz * tx - qx * tz);
        float rz = vz + w * tz + (qx * ty - qy * tx);
        float rc = (c == 0) ? rx : ((c == 1) ? ry : rz);
        out[(long)grow * D_MODEL + gcol] =
            sDecay[row] * rc + (accI[mi][ni][r] + binv);
      }
    }
}

// -------------------------------------------------------------------------
extern "C" void kernel_launch(void* const* d_in, const int* in_sizes, int n_in,
                              void* d_out, int out_size, void* d_ws, size_t ws_size,
                              hipStream_t stream) {
  const float* x     = (const float*)d_in[0];
  const float* hprev = (const float*)d_in[1];
  const float* wbiv  = (const float*)d_in[2];
  const float* bbiv  = (const float*)d_in[3];
  const float* wdec  = (const float*)d_in[4];
  const float* bdec  = (const float*)d_in[5];
  const float* win   = (const float*)d_in[6];
  const float* bin   = (const float*)d_in[7];
  float* out = (float*)d_out;

  const size_t XB_B  = 25165824;   // 8192*1536*2
  const size_t WB_B  = 9437184;    // 2*1536*1536*2
  const size_t DC_B  = 32768;      // 8192*4

  if (ws_size >= XB_B + WB_B + DC_B) {
    char* ws = (char*)d_ws;
    unsigned short* xb = (unsigned short*)ws;
    unsigned short* wb = (unsigned short*)(ws + XB_B);
    float* decay       = (float*)(ws + XB_B + WB_B);
    prep_xd<<<dim3(2048), dim3(256), 0, stream>>>(x, wdec, bdec, xb, decay);
    prep_w<<<dim3(1024), dim3(256), 0, stream>>>(wbiv, win, wb);
    fused_main<<<dim3(NTM * NTN), dim3(512), 0, stream>>>(
        xb, wb, hprev, decay, bbiv, bin, out);
  } else {
    fused_mfma3<<<dim3(NTM * NTN), dim3(256), 0, stream>>>(
        x, wbiv, win, hprev, wdec, bdec, bbiv, bin, out);
  }
}

// Round 16
// 122.972 us; speedup vs baseline: 1.5320x; 1.0182x over previous
//
#include <hip/hip_runtime.h>
#include <cstdint>

#define D_MODEL 1536
#define BATCH   8192
#define EPS     1e-8f

#define BM 128
#define BN 96        // multiple of 3: quaternion blocks never straddle a tile
#define BK 64
#define NT (D_MODEL / BK)    // 24 K-tiles
#define NTN (D_MODEL / BN)   // 16
#define NTM (BATCH / BM)     // 64
#define BUF 40960            // bytes per LDS buffer (A 16384 + B1 12288 + B2 12288)

typedef __attribute__((ext_vector_type(8))) short bf16x8;
typedef __attribute__((ext_vector_type(8))) unsigned short ushort8;
typedef __attribute__((ext_vector_type(4))) float f32x4;

__device__ __forceinline__ unsigned short f2bf(float f) {
  unsigned u = __builtin_bit_cast(unsigned, f);
  u += 0x7fffu + ((u >> 16) & 1u);            // round-to-nearest-even
  return (unsigned short)(u >> 16);
}

__device__ __forceinline__ ushort8 pack8u(float4 a, float4 b) {
  ushort8 o;
  o[0] = f2bf(a.x); o[1] = f2bf(a.y); o[2] = f2bf(a.z); o[3] = f2bf(a.w);
  o[4] = f2bf(b.x); o[5] = f2bf(b.y); o[6] = f2bf(b.z); o[7] = f2bf(b.w);
  return o;
}

__device__ __forceinline__ void full_drain() {
  asm volatile("s_waitcnt vmcnt(0) lgkmcnt(0)" ::: "memory");
}
__device__ __forceinline__ void vm_drain() {
  asm volatile("s_waitcnt vmcnt(0)" ::: "memory");
}
__device__ __forceinline__ void lgkm_drain() {
  asm volatile("s_waitcnt lgkmcnt(0)" ::: "memory");
}

__device__ __forceinline__ void load_lds16(const void* g, void* l) {
  __builtin_amdgcn_global_load_lds(
      (const __attribute__((address_space(1))) unsigned int*)g,
      (__attribute__((address_space(3))) unsigned int*)l,
      16, 0, 0);
}

// ---------------- prep_all: x->bf16 + decay (blocks 0..2047),
//                  weights->bf16 (blocks 2048..3071) ----------------------
__global__ void prep_all(const float* __restrict__ x,
                         const float* __restrict__ wdec,
                         const float* __restrict__ bdec,
                         const float* __restrict__ wbiv,
                         const float* __restrict__ win,
                         unsigned short* __restrict__ xb,
                         unsigned short* __restrict__ wb,
                         float* __restrict__ decay) {
  const int b = blockIdx.x;
  if (b < 2048) {
    // ---- x conversion + decay: one wave per row ----
    int row  = (int)((b * 256 + threadIdx.x) >> 6);
    int lane = threadIdx.x & 63;
    const float4* xr = (const float4*)(x + (long)row * D_MODEL);
    const float4* wr = (const float4*)wdec;
    unsigned short* xo = xb + (long)row * D_MODEL;
    float acc = 0.f;
#pragma unroll
    for (int i = 0; i < 6; ++i) {                // 6*64*4 = 1536
      float4 a = xr[lane + 64 * i];
      float4 w = wr[lane + 64 * i];
      acc += a.x * w.x + a.y * w.y + a.z * w.z + a.w * w.w;
      ushort4 o;
      o.x = f2bf(a.x); o.y = f2bf(a.y); o.z = f2bf(a.z); o.w = f2bf(a.w);
      *(ushort4*)(xo + (lane + 64 * i) * 4) = o;
    }
    for (int off = 32; off; off >>= 1) acc += __shfl_xor(acc, off);
    if (lane == 0) decay[row] = 1.f / (1.f + expf(-(acc + bdec[0])));
  } else {
    // ---- weight conversion: grid-stride over both matrices ----
    const long NW4 = (long)D_MODEL * D_MODEL / 4;   // 589824 float4 per matrix
    for (long i = (long)(b - 2048) * 256 + threadIdx.x; i < 2 * NW4;
         i += (long)1024 * 256) {
      const float4* src = (i < NW4) ? (const float4*)wbiv : (const float4*)win;
      long j = (i < NW4) ? i : (i - NW4);
      float4 v = src[j];
      ushort4 o;
      o.x = f2bf(v.x); o.y = f2bf(v.y); o.z = f2bf(v.z); o.w = f2bf(v.w);
      *(ushort4*)(wb + 4 * i) = o;
    }
  }
}

// ---------------- main: dual-GEMM + quaternion epilogue -------------------
// r15 structure (T3 2-phase double-buffer, per-ks fence regions) + hoisted
// STAGE addressing: 6 per-thread global pointers advanced by BK per tile.
__global__ __launch_bounds__(512, 2)
void fused_main(const unsigned short* __restrict__ xb,
                const unsigned short* __restrict__ wb,
                const float* __restrict__ hprev,
                const float* __restrict__ decay,
                const float* __restrict__ bbiv,
                const float* __restrict__ bin,
                float* __restrict__ out) {
  __shared__ __align__(16) char smem[2 * BUF];   // 81920 B -> 2 blocks/CU
  float* sBv = (float*)smem;                     // [128][97] epilogue overlay

  const int bid = blockIdx.x;
  const int tm = bid / NTN, tn = bid % NTN;
  const int m0 = tm * BM, n0 = tn * BN;
  const int tid  = threadIdx.x;
  const int lane = tid & 63, wid = tid >> 6;
  const int wr = wid >> 1, wc = wid & 1;   // 4x2 wave grid: 32x48 per wave
  const int lr = lane & 15;                // fragment row/col
  const int lk = lane >> 4;                // k-octet group

  // ---- hoisted STAGE addressing (global ptrs advance BK per tile) ----
  const unsigned short *gA0, *gA1, *gB1a, *gB1b, *gB2a, *gB2b;
  int dA0, dA1, dB1a, dB1b, dB2a, dB2b;
  {
    int f, row, c, cs;
    f = tid;        row = f >> 3; c = f & 7; cs = c ^ (row & 7);
    gA0 = xb + (long)(m0 + row) * D_MODEL + cs * 8;
    f = 512 + tid;  row = f >> 3; c = f & 7; cs = c ^ (row & 7);
    gA1 = xb + (long)(m0 + row) * D_MODEL + cs * 8;
    f = tid;        row = f >> 3; c = f & 7; cs = c ^ (row & 7);
    gB1a = wb + (long)(n0 + row) * D_MODEL + cs * 8;
    gB2a = gB1a + (long)D_MODEL * D_MODEL;
    f = 512 + tid;  row = f >> 3; c = f & 7; cs = c ^ (row & 7);
    gB1b = wb + (long)(n0 + row) * D_MODEL + cs * 8;   // used only if tid<256
    gB2b = gB1b + (long)D_MODEL * D_MODEL;
    dA0  = (wid * 64) << 4;
    dA1  = (512 + wid * 64) << 4;
    dB1a = 16384 + ((wid * 64) << 4);
    dB1b = 16384 + ((512 + wid * 64) << 4);
    dB2a = dB1a + 12288;
    dB2b = dB1b + 12288;
  }

  auto STAGE = [&](int bb) {
    load_lds16(gA0,  smem + bb + dA0);
    load_lds16(gA1,  smem + bb + dA1);
    load_lds16(gB1a, smem + bb + dB1a);
    if (tid < 256) load_lds16(gB1b, smem + bb + dB1b);
    load_lds16(gB2a, smem + bb + dB2a);
    if (tid < 256) load_lds16(gB2b, smem + bb + dB2b);
    gA0 += BK; gA1 += BK; gB1a += BK; gB1b += BK; gB2a += BK; gB2b += BK;
  };

  // acc*[mi][ni][r] == C[wr*32+mi*16+lk*4+r][n0+wc*48+ni*16+lr]
  f32x4 accB[2][3], accI[2][3];
#pragma unroll
  for (int a = 0; a < 2; ++a)
#pragma unroll
    for (int b = 0; b < 3; ++b) { accB[a][b] = (f32x4)0.f; accI[a][b] = (f32x4)0.f; }

  // prologue: fill buffer 0
  STAGE(0);
  vm_drain();
  __syncthreads();

  for (int t = 0; t < NT; ++t) {
    const int cur = (t & 1) * BUF;
    if (t + 1 < NT) STAGE(((t + 1) & 1) * BUF);   // prefetch next tile

    const unsigned short* cA  = (const unsigned short*)(smem + cur);
    const unsigned short* cB1 = (const unsigned short*)(smem + cur + 16384);
    const unsigned short* cB2 = (const unsigned short*)(smem + cur + 28672);

#pragma unroll
    for (int ks = 0; ks < 2; ++ks) {
      const int slot = ks * 4 + lk;        // logical k-octet slot (0..7)
      bf16x8 a[2], b1[3], b2[3];
#pragma unroll
      for (int mi = 0; mi < 2; ++mi) {
        int R = wr * 32 + mi * 16 + lr;
        a[mi] = *(const bf16x8*)(cA + R * 64 + (slot ^ (R & 7)) * 8);
      }
#pragma unroll
      for (int ni = 0; ni < 3; ++ni) {
        int R = wc * 48 + ni * 16 + lr;
        b1[ni] = *(const bf16x8*)(cB1 + R * 64 + (slot ^ (R & 7)) * 8);
        b2[ni] = *(const bf16x8*)(cB2 + R * 64 + (slot ^ (R & 7)) * 8);
      }
      lgkm_drain();                          // operands in registers
      __builtin_amdgcn_sched_barrier(0);     // no reorder into MFMA chain
#pragma unroll
      for (int mi = 0; mi < 2; ++mi)
#pragma unroll
        for (int ni = 0; ni < 3; ++ni)
          accB[mi][ni] = __builtin_amdgcn_mfma_f32_16x16x32_bf16(
              a[mi], b1[ni], accB[mi][ni], 0, 0, 0);
      __builtin_amdgcn_sched_barrier(0);     // no chain interleave
#pragma unroll
      for (int mi = 0; mi < 2; ++mi)
#pragma unroll
        for (int ni = 0; ni < 3; ++ni)
          accI[mi][ni] = __builtin_amdgcn_mfma_f32_16x16x32_bf16(
              a[mi], b2[ni], accI[mi][ni], 0, 0, 0);
      __builtin_amdgcn_sched_barrier(0);
    }

    vm_drain();        // prefetched tile landed; LDS reads already drained
    __syncthreads();   // safe to overwrite buffer (t&1) next iteration
  }

  // ---- epilogue (r15 logic) ----
#pragma unroll
  for (int mi = 0; mi < 2; ++mi)
#pragma unroll
    for (int ni = 0; ni < 3; ++ni) {
      int col = wc * 48 + ni * 16 + lr;
      float bb = bbiv[n0 + col];
#pragma unroll
      for (int r = 0; r < 4; ++r) {
        int row = wr * 32 + mi * 16 + lk * 4 + r;
        sBv[row * 97 + col] = accB[mi][ni][r] + bb;
      }
    }
  full_drain();
  __syncthreads();

#pragma unroll
  for (int mi = 0; mi < 2; ++mi)
#pragma unroll
    for (int ni = 0; ni < 3; ++ni) {
      int col  = wc * 48 + ni * 16 + lr;
      int gcol = n0 + col;
      int c    = (col % 3);        // n0 % 3 == 0
      int lc0  = col - c;
      float binv = bin[gcol];
#pragma unroll
      for (int r = 0; r < 4; ++r) {
        int row  = wr * 32 + mi * 16 + lk * 4 + r;
        int grow = m0 + row;
        float bx = sBv[row * 97 + lc0];
        float by = sBv[row * 97 + lc0 + 1];
        float bz = sBv[row * 97 + lc0 + 2];
        const float* hp = hprev + (long)grow * D_MODEL + (n0 + lc0);
        float vx = hp[0], vy = hp[1], vz = hp[2];
        float nb = sqrtf(bx * bx + by * by + bz * bz);
        nb = fmaxf(nb, EPS);
        float ha = 0.5f * nb;
        float w  = cosf(ha);
        float s  = sinf(ha) / nb;
        // faithful to reference quirk: qx from bz, qy from -by, qz from bx
        float qx = s * bz, qy = -s * by, qz = s * bx;
        float tx = 2.f * (qy * vz - qz * vy);
        float ty = 2.f * (qz * vx - qx * vz);
        float tz = 2.f * (qx * vy - qy * vx);
        float rx = vx + w * tx + (qy * tz - qz * ty);
        float ry = vy + w * ty + (qz * tx - qx * tz);
        float rz = vz + w * tz + (qx * ty - qy * tx);
        float rc = (c == 0) ? rx : ((c == 1) ? ry : rz);
        out[(long)grow * D_MODEL + gcol] =
            decay[grow] * rc + (accI[mi][ni][r] + binv);
      }
    }
}

// ---------------- fallback (r7 green kernel, hammers retained) ------------
__global__ __launch_bounds__(256, 2)
void fused_mfma3(const float* __restrict__ x,
                 const float* __restrict__ wbiv,
                 const float* __restrict__ win,
                 const float* __restrict__ hprev,
                 const float* __restrict__ wdec,
                 const float* __restrict__ bdec,
                 const float* __restrict__ bbiv,
                 const float* __restrict__ bin,
                 float* __restrict__ out) {
  __shared__ __align__(16) char smem[50688];
  __shared__ float sDecay[BM];
  unsigned short* sA  = (unsigned short*)smem;
  unsigned short* sB1 = (unsigned short*)(smem + 16384);
  unsigned short* sB2 = (unsigned short*)(smem + 28672);
  float* sBv = (float*)smem;

  const int bid = blockIdx.x;
  const int tm = bid / NTN, tn = bid % NTN;
  const int m0 = tm * BM, n0 = tn * BN;
  const int tid  = threadIdx.x;
  const int lane = tid & 63, wid = tid >> 6;
  const int wr = wid >> 1, wc = wid & 1;
  const int lr = lane & 15;
  const int lk = lane >> 4;

  {
    const float bd = bdec[0];
    const float4* wd4 = (const float4*)wdec;
    for (int rr = 0; rr < 32; ++rr) {
      int row = wid * 32 + rr;
      const float4* xr = (const float4*)(x + (long)(m0 + row) * D_MODEL);
      float acc = 0.f;
#pragma unroll
      for (int i = 0; i < 6; ++i) {
        float4 a = xr[lane + 64 * i];
        float4 b = wd4[lane + 64 * i];
        acc += a.x * b.x + a.y * b.y + a.z * b.z + a.w * b.w;
      }
      for (int off = 32; off; off >>= 1) acc += __shfl_xor(acc, off);
      if (lane == 0) sDecay[row] = 1.f / (1.f + expf(-(acc + bd)));
    }
  }

  f32x4 accB[4][3], accI[4][3];
#pragma unroll
  for (int a = 0; a < 4; ++a)
#pragma unroll
    for (int b = 0; b < 3; ++b) { accB[a][b] = (f32x4)0.f; accI[a][b] = (f32x4)0.f; }

  for (int kt = 0; kt < D_MODEL; kt += BK) {
    full_drain();
    __syncthreads();
#pragma unroll
    for (int i = 0; i < 4; ++i) {
      int f = i * 256 + tid;
      int row = f >> 3, c = f & 7;
      const float4* p = (const float4*)(x + (long)(m0 + row) * D_MODEL + kt + c * 8);
      *(ushort8*)(sA + row * 64 + c * 8) = pack8u(p[0], p[1]);
    }
#pragma unroll
    for (int i = 0; i < 6; ++i) {
      int mat = (i >= 3);
      int g = (i - 3 * mat) * 256 + tid;
      int row = g >> 3, c = g & 7;
      const float* wsrc = mat ? win : wbiv;
      const float4* p = (const float4*)(wsrc + (long)(n0 + row) * D_MODEL + kt + c * 8);
      *(ushort8*)((mat ? sB2 : sB1) + row * 64 + c * 8) = pack8u(p[0], p[1]);
    }
    full_drain();
    __syncthreads();

#pragma unroll
    for (int ks = 0; ks < 2; ++ks) {
      const int k0 = ks * 32 + lk * 8;
      bf16x8 a[4], b1[3], b2[3];
#pragma unroll
      for (int mi = 0; mi < 4; ++mi)
        a[mi] = *(const bf16x8*)(sA + (wr * 64 + mi * 16 + lr) * 64 + k0);
#pragma unroll
      for (int ni = 0; ni < 3; ++ni) {
        b1[ni] = *(const bf16x8*)(sB1 + (wc * 48 + ni * 16 + lr) * 64 + k0);
        b2[ni] = *(const bf16x8*)(sB2 + (wc * 48 + ni * 16 + lr) * 64 + k0);
      }
      full_drain();
      __builtin_amdgcn_sched_barrier(0);
#pragma unroll
      for (int mi = 0; mi < 4; ++mi)
#pragma unroll
        for (int ni = 0; ni < 3; ++ni)
          accB[mi][ni] = __builtin_amdgcn_mfma_f32_16x16x32_bf16(
              a[mi], b1[ni], accB[mi][ni], 0, 0, 0);
      __builtin_amdgcn_sched_barrier(0);
#pragma unroll
      for (int mi = 0; mi < 4; ++mi)
#pragma unroll
        for (int ni = 0; ni < 3; ++ni)
          accI[mi][ni] = __builtin_amdgcn_mfma_f32_16x16x32_bf16(
              a[mi], b2[ni], accI[mi][ni], 0, 0, 0);
      __builtin_amdgcn_sched_barrier(0);
    }
  }

  full_drain();
  __syncthreads();
#pragma unroll
  for (int mi = 0; mi < 4; ++mi)
#pragma unroll
    for (int ni = 0; ni < 3; ++ni) {
      int col = wc * 48 + ni * 16 + lr;
      float bb = bbiv[n0 + col];
#pragma unroll
      for (int r = 0; r < 4; ++r) {
        int row = wr * 64 + mi * 16 + lk * 4 + r;
        sBv[row * 97 + col] = accB[mi][ni][r] + bb;
      }
    }
  full_drain();
  __syncthreads();

#pragma unroll
  for (int mi = 0; mi < 4; ++mi)
#pragma unroll
    for (int ni = 0; ni < 3; ++ni) {
      int col  = wc * 48 + ni * 16 + lr;
      int gcol = n0 + col;
      int c    = (col % 3);
      int lc0  = col - c;
      float binv = bin[gcol];
#pragma unroll
      for (int r = 0; r < 4; ++r) {
        int row  = wr * 64 + mi * 16 + lk * 4 + r;
        int grow = m0 + row;
        float bx = sBv[row * 97 + lc0];
        float by = sBv[row * 97 + lc0 + 1];
        float bz = sBv[row * 97 + lc0 + 2];
        const float* hp = hprev + (long)grow * D_MODEL + (n0 + lc0);
        float vx = hp[0], vy = hp[1], vz = hp[2];
        float nb = sqrtf(bx * bx + by * by + bz * bz);
        nb = fmaxf(nb, EPS);
        float ha = 0.5f * nb;
        float w  = cosf(ha);
        float s  = sinf(ha) / nb;
        float qx = s * bz, qy = -s * by, qz = s * bx;
        float tx = 2.f * (qy * vz - qz * vy);
        float ty = 2.f * (qz * vx - qx * vz);
        float tz = 2.f * (qx * vy - qy * vx);
        float rx = vx + w * tx + (qy * tz - qz * ty);
        float ry = vy + w * ty + (qz * tx - qx * tz);
        float rz = vz + w * tz + (qx * ty - qy * tx);
        float rc = (c == 0) ? rx : ((c == 1) ? ry : rz);
        out[(long)grow * D_MODEL + gcol] =
            sDecay[row] * rc + (accI[mi][ni][r] + binv);
      }
    }
}

// -------------------------------------------------------------------------
extern "C" void kernel_launch(void* const* d_in, const int* in_sizes, int n_in,
                              void* d_out, int out_size, void* d_ws, size_t ws_size,
                              hipStream_t stream) {
  const float* x     = (const float*)d_in[0];
  const float* hprev = (const float*)d_in[1];
  const float* wbiv  = (const float*)d_in[2];
  const float* bbiv  = (const float*)d_in[3];
  const float* wdec  = (const float*)d_in[4];
  const float* bdec  = (const float*)d_in[5];
  const float* win   = (const float*)d_in[6];
  const float* bin   = (const float*)d_in[7];
  float* out = (float*)d_out;

  const size_t XB_B  = 25165824;   // 8192*1536*2
  const size_t WB_B  = 9437184;    // 2*1536*1536*2
  const size_t DC_B  = 32768;      // 8192*4

  if (ws_size >= XB_B + WB_B + DC_B) {
    char* ws = (char*)d_ws;
    unsigned short* xb = (unsigned short*)ws;
    unsigned short* wb = (unsigned short*)(ws + XB_B);
    float* decay       = (float*)(ws + XB_B + WB_B);
    prep_all<<<dim3(3072), dim3(256), 0, stream>>>(
        x, wdec, bdec, wbiv, win, xb, wb, decay);
    fused_main<<<dim3(NTM * NTN), dim3(512), 0, stream>>>(
        xb, wb, hprev, decay, bbiv, bin, out);
  } else {
    fused_mfma3<<<dim3(NTM * NTN), dim3(256), 0, stream>>>(
        x, wbiv, win, hprev, wdec, bdec, bbiv, bin, out);
  }
}